// Round 2
// baseline (337.500 us; speedup 1.0000x reference)
//
#include <hip/hip_runtime.h>

// MergeAdapter: out = x + Up_n(relu(Down_n(x)))  with per-instance merged
// expert weights w_n = sum_k prob[n,k] * W_k.
// N=16 instances, S=2048, H=1024, K_exp=8, D=256.
// Harness dtypes: ALL inputs fp32 (per reference), output fp32.
// Internally: merged weights + activations in bf16 for MFMA, fp32 accumulate,
// fp32 residual add (residual path has zero rounding error).
//
// Pipeline:
//   k0: merge fp32 experts -> ws (Wd bf16 16x256x1024, Wu bf16 16x1024x256,
//                                 bd f32 16x256, bu f32 16x1024)
//   k1: R = relu(bf16(x) @ Wd^T + bd)        (M=2048,N=256,K=1024) bf16 out
//   k2: out = x + (R @ Wu^T + bu)            (M=2048,N=1024,K=256) fp32 out
// GEMM structure: m97 ladder (128x128 tile, BK=64, global_load_lds w=16 for
// bf16 operands, manual cvt+ds_write for the fp32 A operand, 16x16x32 bf16
// MFMA, 4 waves each 64x64 = 4x4 acc tiles).

typedef unsigned short u16;
typedef __bf16 bf16x8 __attribute__((ext_vector_type(8)));
typedef float f32x4 __attribute__((ext_vector_type(4)));

__device__ __forceinline__ u16 f2bf(float f) {
    union { float f; unsigned int i; } v; v.f = f;
    unsigned int r = v.i + 0x7fffu + ((v.i >> 16) & 1u);  // RNE
    return (u16)(r >> 16);
}

__device__ __forceinline__ void gload_lds16(const u16* g, u16* l) {
    __builtin_amdgcn_global_load_lds(
        (const __attribute__((address_space(1))) void*)g,
        (__attribute__((address_space(3))) void*)l,
        16, 0, 0);
}

// ---------------------------------------------------------------------------
// Kernel 0: merge weights + biases (fp32 in, bf16 weights / fp32 biases out).
// 256 blocks weights + 80 blocks biases. Each weight-thread owns one 8-elem
// vector slot: reads it once per expert (8x 32B), writes 16 merged instances.
// ---------------------------------------------------------------------------
__global__ __launch_bounds__(256)
void merge_kernel(const float* __restrict__ prob,
                  const float* __restrict__ w_down, const float* __restrict__ b_down,
                  const float* __restrict__ w_up,   const float* __restrict__ b_up,
                  u16* __restrict__ Wd, u16* __restrict__ Wu,
                  float* __restrict__ bd, float* __restrict__ bu)
{
    __shared__ float sp[128];          // prob (16 x 8)
    const int tid = threadIdx.x;
    if (tid < 128) sp[tid] = prob[tid];
    __syncthreads();

    const int bid = blockIdx.x;
    const int E = 256 * 1024;          // elems per expert matrix (both shapes)

    if (bid < 256) {
        int v = bid * 256 + tid;       // 0..65535 vector slots (8 elems each)
        const bool down = (v < 32768);
        const int vv = down ? v : (v - 32768);
        const float* W = down ? w_down : w_up;
        u16* O = down ? Wd : Wu;
        const size_t e = (size_t)vv * 8;

        float wf[8][8];
        #pragma unroll
        for (int k = 0; k < 8; ++k) {
            const float4 f0 = *(const float4*)(W + (size_t)k * E + e);
            const float4 f1 = *(const float4*)(W + (size_t)k * E + e + 4);
            wf[k][0] = f0.x; wf[k][1] = f0.y; wf[k][2] = f0.z; wf[k][3] = f0.w;
            wf[k][4] = f1.x; wf[k][5] = f1.y; wf[k][6] = f1.z; wf[k][7] = f1.w;
        }
        for (int n = 0; n < 16; ++n) {
            float a[8] = {0.f,0.f,0.f,0.f,0.f,0.f,0.f,0.f};
            #pragma unroll
            for (int k = 0; k < 8; ++k) {
                const float p = sp[n * 8 + k];
                #pragma unroll
                for (int j = 0; j < 8; ++j) a[j] = fmaf(p, wf[k][j], a[j]);
            }
            union { uint4 u; u16 s[8]; } ov;
            #pragma unroll
            for (int j = 0; j < 8; ++j) ov.s[j] = f2bf(a[j]);
            *(uint4*)(O + (size_t)n * E + e) = ov.u;
        }
    } else {
        int idx = (bid - 256) * 256 + tid;   // 0..20479
        if (idx < 16 * 256) {                // merged b_down (16,256) fp32
            const int n = idx >> 8, d = idx & 255;
            float s = 0.f;
            #pragma unroll
            for (int k = 0; k < 8; ++k)
                s = fmaf(sp[n * 8 + k], b_down[k * 256 + d], s);
            bd[idx] = s;
        } else {                             // merged b_up (16,1024) fp32
            const int i2 = idx - 4096;       // 0..16383
            const int n = i2 >> 10, h = i2 & 1023;
            float s = 0.f;
            #pragma unroll
            for (int k = 0; k < 8; ++k)
                s = fmaf(sp[n * 8 + k], b_up[k * 1024 + h], s);
            bu[i2] = s;
        }
    }
}

// ---------------------------------------------------------------------------
// Down GEMM: R = relu(bf16(A_fp32) @ B_bf16^T + bias).  M=2048,Nn=256,K=1024.
// A staged via fp32 load + cvt + ds_write_b128; B via global_load_lds w=16.
// ---------------------------------------------------------------------------
__global__ __launch_bounds__(256, 2)
void gemm_down(const float* __restrict__ A, const u16* __restrict__ B,
               const float* __restrict__ bias, u16* __restrict__ C,
               int M, int Nn, int K)
{
    __shared__ __align__(16) u16 As[128 * 64];
    __shared__ __align__(16) u16 Bs[128 * 64];

    const int batch = blockIdx.z;
    A += (size_t)batch * M * K;
    B += (size_t)batch * Nn * K;
    bias += (size_t)batch * Nn;
    C += (size_t)batch * M * Nn;

    const int tid = threadIdx.x;
    const int lane = tid & 63;
    const int wave = tid >> 6;
    const int wm = wave >> 1, wn = wave & 1;
    const int quad = lane >> 4, rl = lane & 15;
    const int tm = blockIdx.y, tn = blockIdx.x;

    const float* Ag = A + (size_t)tm * 128 * K;
    const u16* Bg = B + (size_t)tn * 128 * K;

    f32x4 acc[4][4] = {};

    for (int k0 = 0; k0 < K; k0 += 64) {
        // B tile: async DMA, wave-uniform LDS base + lane*16B
        #pragma unroll
        for (int r = 0; r < 4; ++r) {
            const int li = r * 256 + tid;
            const int row = li >> 3;
            const int col = (li & 7) * 8;
            const int ldsbase = (r * 256 + (tid & 192)) * 8;  // wave-uniform
            gload_lds16(Bg + (size_t)row * K + (k0 + col), &Bs[ldsbase]);
        }
        // A tile: fp32 load -> bf16 cvt -> ds_write_b128 (overlaps with B DMA)
        #pragma unroll
        for (int r = 0; r < 4; ++r) {
            const int li = r * 256 + tid;
            const int row = li >> 3;
            const int col = (li & 7) * 8;
            const float4 f0 = *(const float4*)(Ag + (size_t)row * K + (k0 + col));
            const float4 f1 = *(const float4*)(Ag + (size_t)row * K + (k0 + col) + 4);
            union { uint4 u; u16 s[8]; } cv;
            cv.s[0] = f2bf(f0.x); cv.s[1] = f2bf(f0.y);
            cv.s[2] = f2bf(f0.z); cv.s[3] = f2bf(f0.w);
            cv.s[4] = f2bf(f1.x); cv.s[5] = f2bf(f1.y);
            cv.s[6] = f2bf(f1.z); cv.s[7] = f2bf(f1.w);
            *(uint4*)(As + (size_t)li * 8) = cv.u;
        }
        __syncthreads();

        #pragma unroll
        for (int kk = 0; kk < 64; kk += 32) {
            bf16x8 af[4], bfr[4];
            #pragma unroll
            for (int mi = 0; mi < 4; ++mi)
                af[mi] = *(const bf16x8*)(As + (wm * 64 + mi * 16 + rl) * 64 + kk + quad * 8);
            #pragma unroll
            for (int ni = 0; ni < 4; ++ni)
                bfr[ni] = *(const bf16x8*)(Bs + (wn * 64 + ni * 16 + rl) * 64 + kk + quad * 8);
            #pragma unroll
            for (int mi = 0; mi < 4; ++mi)
                #pragma unroll
                for (int ni = 0; ni < 4; ++ni)
                    acc[mi][ni] = __builtin_amdgcn_mfma_f32_16x16x32_bf16(
                        af[mi], bfr[ni], acc[mi][ni], 0, 0, 0);
        }
        __syncthreads();
    }

    // epilogue: D col = rl, row = quad*4+i (m89-verified mapping)
    #pragma unroll
    for (int ni = 0; ni < 4; ++ni) {
        const int col = tn * 128 + wn * 64 + ni * 16 + rl;
        const float bv = bias[col];
        #pragma unroll
        for (int mi = 0; mi < 4; ++mi) {
            #pragma unroll
            for (int i = 0; i < 4; ++i) {
                const int row = tm * 128 + wm * 64 + mi * 16 + quad * 4 + i;
                float v = fmaxf(acc[mi][ni][i] + bv, 0.0f);
                C[(size_t)row * Nn + col] = f2bf(v);
            }
        }
    }
}

// ---------------------------------------------------------------------------
// Up GEMM: out = Res_fp32 + (A_bf16 @ B_bf16^T + bias).  M=2048,Nn=1024,K=256.
// Both operands bf16 via global_load_lds. fp32 residual + fp32 store.
// ---------------------------------------------------------------------------
__global__ __launch_bounds__(256, 2)
void gemm_up(const u16* __restrict__ A, const u16* __restrict__ B,
             const float* __restrict__ bias, const float* __restrict__ Res,
             float* __restrict__ C, int M, int Nn, int K)
{
    __shared__ __align__(16) u16 As[128 * 64];
    __shared__ __align__(16) u16 Bs[128 * 64];

    const int batch = blockIdx.z;
    A += (size_t)batch * M * K;
    B += (size_t)batch * Nn * K;
    bias += (size_t)batch * Nn;
    Res += (size_t)batch * M * Nn;
    C += (size_t)batch * M * Nn;

    const int tid = threadIdx.x;
    const int lane = tid & 63;
    const int wave = tid >> 6;
    const int wm = wave >> 1, wn = wave & 1;
    const int quad = lane >> 4, rl = lane & 15;
    const int tm = blockIdx.y, tn = blockIdx.x;

    const u16* Ag = A + (size_t)tm * 128 * K;
    const u16* Bg = B + (size_t)tn * 128 * K;

    f32x4 acc[4][4] = {};

    for (int k0 = 0; k0 < K; k0 += 64) {
        #pragma unroll
        for (int r = 0; r < 4; ++r) {
            const int li = r * 256 + tid;
            const int row = li >> 3;
            const int col = (li & 7) * 8;
            const int ldsbase = (r * 256 + (tid & 192)) * 8;  // wave-uniform
            gload_lds16(Ag + (size_t)row * K + (k0 + col), &As[ldsbase]);
        }
        #pragma unroll
        for (int r = 0; r < 4; ++r) {
            const int li = r * 256 + tid;
            const int row = li >> 3;
            const int col = (li & 7) * 8;
            const int ldsbase = (r * 256 + (tid & 192)) * 8;
            gload_lds16(Bg + (size_t)row * K + (k0 + col), &Bs[ldsbase]);
        }
        __syncthreads();

        #pragma unroll
        for (int kk = 0; kk < 64; kk += 32) {
            bf16x8 af[4], bfr[4];
            #pragma unroll
            for (int mi = 0; mi < 4; ++mi)
                af[mi] = *(const bf16x8*)(As + (wm * 64 + mi * 16 + rl) * 64 + kk + quad * 8);
            #pragma unroll
            for (int ni = 0; ni < 4; ++ni)
                bfr[ni] = *(const bf16x8*)(Bs + (wn * 64 + ni * 16 + rl) * 64 + kk + quad * 8);
            #pragma unroll
            for (int mi = 0; mi < 4; ++mi)
                #pragma unroll
                for (int ni = 0; ni < 4; ++ni)
                    acc[mi][ni] = __builtin_amdgcn_mfma_f32_16x16x32_bf16(
                        af[mi], bfr[ni], acc[mi][ni], 0, 0, 0);
        }
        __syncthreads();
    }

    #pragma unroll
    for (int ni = 0; ni < 4; ++ni) {
        const int col = tn * 128 + wn * 64 + ni * 16 + rl;
        const float bv = bias[col];
        #pragma unroll
        for (int mi = 0; mi < 4; ++mi) {
            #pragma unroll
            for (int i = 0; i < 4; ++i) {
                const int row = tm * 128 + wm * 64 + mi * 16 + quad * 4 + i;
                const size_t off = (size_t)row * Nn + col;
                C[off] = acc[mi][ni][i] + bv + Res[off];
            }
        }
    }
}

// ---------------------------------------------------------------------------
extern "C" void kernel_launch(void* const* d_in, const int* in_sizes, int n_in,
                              void* d_out, int out_size, void* d_ws, size_t ws_size,
                              hipStream_t stream) {
    const float* hidden = (const float*)d_in[0];   // (16, 2048, 1024) fp32
    const float* prob   = (const float*)d_in[1];   // (16, 8) fp32
    const float* w_down = (const float*)d_in[2];   // (8, 256, 1024) fp32
    const float* b_down = (const float*)d_in[3];   // (8, 256) fp32
    const float* w_up   = (const float*)d_in[4];   // (8, 1024, 256) fp32
    const float* b_up   = (const float*)d_in[5];   // (8, 1024) fp32
    float* out = (float*)d_out;                    // (16, 2048, 1024) fp32

    // workspace layout (~32.1 MB)
    u16* Wd = (u16*)d_ws;                               // 16*256*1024 bf16 = 8 MB
    u16* Wu = Wd + (size_t)16 * 256 * 1024;             // 8 MB
    u16* R  = Wu + (size_t)16 * 1024 * 256;             // 16*2048*256 bf16 = 16 MB
    float* bd = (float*)(R + (size_t)16 * 2048 * 256);  // 16 KB
    float* bu = bd + 16 * 256;                          // 64 KB

    merge_kernel<<<336, 256, 0, stream>>>(prob, w_down, b_down, w_up, b_up,
                                          Wd, Wu, bd, bu);

    // down: M=2048, Nn=256, K=1024, batched over 16 instances
    gemm_down<<<dim3(2, 16, 16), 256, 0, stream>>>(
        hidden, Wd, bd, R, 2048, 256, 1024);

    // up: M=2048, Nn=1024, K=256, residual = hidden (fp32)
    gemm_up<<<dim3(8, 16, 16), 256, 0, stream>>>(
        R, Wu, bu, hidden, out, 2048, 1024, 256);
}

// Round 3
// 331.713 us; speedup vs baseline: 1.0174x; 1.0174x over previous
//
#include <hip/hip_runtime.h>

// MergeAdapter: out = x + Up_n(relu(Down_n(x))), merged expert weights.
// N=16, S=2048, H=1024, Kexp=8, D=256. fp32 in/out, bf16 MFMA internally.
//
// Round 3: fused adapter kernel. Grid = 256 blocks (1/CU), 512 thr = 8 waves.
// Each block owns one (batch, 128-row) slice:
//   phase 1: R = relu(x_blk @ Wd^T + bd)  (128x256) -> LDS (bf16, 64 KB)
//   phase 2: 8 chunks of 128 out-cols: out = x + R @ Wu_chunk^T + bu
// R never touches HBM; x read twice (GEMM A + fp32 residual); weights stay
// L2-resident via XCD-pinned batch swizzle (batch = f(blockIdx%16)).
// LDS total = 64 KB (R) + 64 KB (stage union: p1 xs 16K+wds 32K / p2 wus 64K).

typedef unsigned short u16;
typedef __bf16 bf16x8 __attribute__((ext_vector_type(8)));
typedef float f32x4 __attribute__((ext_vector_type(4)));

__device__ __forceinline__ u16 f2bf(float f) {
    union { float f; unsigned int i; } v; v.f = f;
    unsigned int r = v.i + 0x7fffu + ((v.i >> 16) & 1u);  // RNE
    return (u16)(r >> 16);
}

__device__ __forceinline__ void gload_lds16(const u16* g, u16* l) {
    __builtin_amdgcn_global_load_lds(
        (const __attribute__((address_space(1))) void*)g,
        (__attribute__((address_space(3))) void*)l,
        16, 0, 0);
}

// ---------------------------------------------------------------------------
// Kernel 0: merge weights + biases (fp32 in -> bf16 weights / fp32 biases).
// ---------------------------------------------------------------------------
__global__ __launch_bounds__(256)
void merge_kernel(const float* __restrict__ prob,
                  const float* __restrict__ w_down, const float* __restrict__ b_down,
                  const float* __restrict__ w_up,   const float* __restrict__ b_up,
                  u16* __restrict__ Wd, u16* __restrict__ Wu,
                  float* __restrict__ bd, float* __restrict__ bu)
{
    __shared__ float sp[128];          // prob (16 x 8)
    const int tid = threadIdx.x;
    if (tid < 128) sp[tid] = prob[tid];
    __syncthreads();

    const int bid = blockIdx.x;
    const int E = 256 * 1024;

    if (bid < 256) {
        int v = bid * 256 + tid;       // 0..65535 vector slots (8 elems each)
        const bool down = (v < 32768);
        const int vv = down ? v : (v - 32768);
        const float* W = down ? w_down : w_up;
        u16* O = down ? Wd : Wu;
        const size_t e = (size_t)vv * 8;

        float wf[8][8];
        #pragma unroll
        for (int k = 0; k < 8; ++k) {
            const float4 f0 = *(const float4*)(W + (size_t)k * E + e);
            const float4 f1 = *(const float4*)(W + (size_t)k * E + e + 4);
            wf[k][0] = f0.x; wf[k][1] = f0.y; wf[k][2] = f0.z; wf[k][3] = f0.w;
            wf[k][4] = f1.x; wf[k][5] = f1.y; wf[k][6] = f1.z; wf[k][7] = f1.w;
        }
        for (int n = 0; n < 16; ++n) {
            float a[8] = {0.f,0.f,0.f,0.f,0.f,0.f,0.f,0.f};
            #pragma unroll
            for (int k = 0; k < 8; ++k) {
                const float p = sp[n * 8 + k];
                #pragma unroll
                for (int j = 0; j < 8; ++j) a[j] = fmaf(p, wf[k][j], a[j]);
            }
            union { uint4 u; u16 s[8]; } ov;
            #pragma unroll
            for (int j = 0; j < 8; ++j) ov.s[j] = f2bf(a[j]);
            *(uint4*)(O + (size_t)n * E + e) = ov.u;
        }
    } else {
        int idx = (bid - 256) * 256 + tid;   // 0..20479
        if (idx < 16 * 256) {
            const int n = idx >> 8, d = idx & 255;
            float s = 0.f;
            #pragma unroll
            for (int k = 0; k < 8; ++k)
                s = fmaf(sp[n * 8 + k], b_down[k * 256 + d], s);
            bd[idx] = s;
        } else {
            const int i2 = idx - 4096;
            const int n = i2 >> 10, h = i2 & 1023;
            float s = 0.f;
            #pragma unroll
            for (int k = 0; k < 8; ++k)
                s = fmaf(sp[n * 8 + k], b_up[k * 1024 + h], s);
            bu[i2] = s;
        }
    }
}

// ---------------------------------------------------------------------------
// Fused adapter kernel.
// ---------------------------------------------------------------------------
__global__ __launch_bounds__(512, 1)
void fused_adapter(const float* __restrict__ x, const u16* __restrict__ Wd,
                   const u16* __restrict__ Wu, const float* __restrict__ bd,
                   const float* __restrict__ bu, float* __restrict__ out)
{
    __shared__ __align__(16) u16 Rs[128 * 256];     // 64 KB: R in bf16
    __shared__ __align__(16) u16 stage[32768];      // 64 KB union

    const int tid  = threadIdx.x;
    const int lane = tid & 63;
    const int wave = tid >> 6;               // 0..7
    const int quad = lane >> 4, rl = lane & 15;

    // swizzle: each batch's 16 M-blocks share one XCD (id%8) -> Wd/Wu L2-hot
    const int id = blockIdx.x;               // 0..255
    const int r4 = id & 15;
    const int batch = (r4 & 7) * 2 + (r4 >> 3);
    const int mblk  = id >> 4;               // 0..15

    const float* xb  = x  + (size_t)batch * 2048 * 1024 + (size_t)mblk * 128 * 1024;
    const u16*   Wdb = Wd + (size_t)batch * 256 * 1024;
    const u16*   Wub = Wu + (size_t)batch * 1024 * 256;
    const float* bdb = bd + batch * 256;
    const float* bub = bu + batch * 1024;
    float*       ob  = out + (size_t)batch * 2048 * 1024 + (size_t)mblk * 128 * 1024;

    u16* xs  = stage;          // phase 1: 128x64 bf16 (16 KB)
    u16* wds = stage + 8192;   // phase 1: 256x64 bf16 (32 KB)

    // ======================= phase 1: R = relu(x @ Wd^T + bd) ==============
    const int wm1 = wave >> 2, wn1 = wave & 3;   // 2x4 wave grid over 128x256
    f32x4 acc1[4][4] = {};

    for (int k0 = 0; k0 < 1024; k0 += 64) {
        // Wd tile 256x64 via async DMA (16 B/lane, wave-uniform base)
        #pragma unroll
        for (int rr = 0; rr < 4; ++rr) {
            const int li  = rr * 512 + tid;
            const int row = li >> 3, col = (li & 7) * 8;
            gload_lds16(Wdb + (size_t)row * 1024 + (k0 + col),
                        wds + (size_t)(rr * 512 + wave * 64) * 8);
        }
        // x tile 128x64: fp32 load -> bf16 cvt -> ds_write_b128
        #pragma unroll
        for (int rr = 0; rr < 2; ++rr) {
            const int li  = rr * 512 + tid;
            const int row = li >> 3, col = (li & 7) * 8;
            const float4 f0 = *(const float4*)(xb + (size_t)row * 1024 + (k0 + col));
            const float4 f1 = *(const float4*)(xb + (size_t)row * 1024 + (k0 + col) + 4);
            union { uint4 u; u16 s[8]; } cv;
            cv.s[0]=f2bf(f0.x); cv.s[1]=f2bf(f0.y); cv.s[2]=f2bf(f0.z); cv.s[3]=f2bf(f0.w);
            cv.s[4]=f2bf(f1.x); cv.s[5]=f2bf(f1.y); cv.s[6]=f2bf(f1.z); cv.s[7]=f2bf(f1.w);
            *(uint4*)(xs + (size_t)li * 8) = cv.u;
        }
        __syncthreads();

        #pragma unroll
        for (int kk = 0; kk < 64; kk += 32) {
            bf16x8 af[4], bfv[4];
            #pragma unroll
            for (int mi = 0; mi < 4; ++mi)
                af[mi] = *(const bf16x8*)(xs + (wm1 * 64 + mi * 16 + rl) * 64 + kk + quad * 8);
            #pragma unroll
            for (int ni = 0; ni < 4; ++ni)
                bfv[ni] = *(const bf16x8*)(wds + (wn1 * 64 + ni * 16 + rl) * 64 + kk + quad * 8);
            #pragma unroll
            for (int mi = 0; mi < 4; ++mi)
                #pragma unroll
                for (int ni = 0; ni < 4; ++ni)
                    acc1[mi][ni] = __builtin_amdgcn_mfma_f32_16x16x32_bf16(
                        af[mi], bfv[ni], acc1[mi][ni], 0, 0, 0);
        }
        __syncthreads();
    }

    // epilogue 1: bias + relu -> Rs (row-major, K=256 contiguous = A layout)
    #pragma unroll
    for (int ni = 0; ni < 4; ++ni) {
        const int col = wn1 * 64 + ni * 16 + rl;       // d index
        const float bv = bdb[col];
        #pragma unroll
        for (int mi = 0; mi < 4; ++mi) {
            #pragma unroll
            for (int i = 0; i < 4; ++i) {
                const int row = wm1 * 64 + mi * 16 + quad * 4 + i;
                Rs[row * 256 + col] = f2bf(fmaxf(acc1[mi][ni][i] + bv, 0.0f));
            }
        }
    }

    // ======================= phase 2: out = x + R @ Wu^T + bu ==============
    const int wm2 = wave >> 2, wn2 = wave & 3;   // 2x4 wave grid over 128x128

    for (int c = 0; c < 8; ++c) {
        __syncthreads();   // Rs complete (c=0) / stage free from prev chunk

        // Wu chunk: rows c*128..+127 (out cols), all K=256 -> 64 KB
        #pragma unroll
        for (int rr = 0; rr < 8; ++rr) {
            const int li  = rr * 512 + tid;
            const int row = li >> 5, col = (li & 31) * 8;
            gload_lds16(Wub + (size_t)(c * 128 + row) * 256 + col,
                        stage + (size_t)(rr * 512 + wave * 64) * 8);
        }
        __syncthreads();

        f32x4 acc2[4][2] = {};
        #pragma unroll
        for (int kk = 0; kk < 256; kk += 32) {
            bf16x8 af[4], bfv[2];
            #pragma unroll
            for (int mi = 0; mi < 4; ++mi)
                af[mi] = *(const bf16x8*)(Rs + (wm2 * 64 + mi * 16 + rl) * 256 + kk + quad * 8);
            #pragma unroll
            for (int ni = 0; ni < 2; ++ni)
                bfv[ni] = *(const bf16x8*)(stage + (wn2 * 32 + ni * 16 + rl) * 256 + kk + quad * 8);
            #pragma unroll
            for (int mi = 0; mi < 4; ++mi)
                #pragma unroll
                for (int ni = 0; ni < 2; ++ni)
                    acc2[mi][ni] = __builtin_amdgcn_mfma_f32_16x16x32_bf16(
                        af[mi], bfv[ni], acc2[mi][ni], 0, 0, 0);
        }

        // epilogue 2: bias + fp32 residual -> fp32 out
        #pragma unroll
        for (int ni = 0; ni < 2; ++ni) {
            const int colg = c * 128 + wn2 * 32 + ni * 16 + rl;
            const float bv = bub[colg];
            #pragma unroll
            for (int mi = 0; mi < 4; ++mi) {
                #pragma unroll
                for (int i = 0; i < 4; ++i) {
                    const int rowl = wm2 * 64 + mi * 16 + quad * 4 + i;
                    const size_t off = (size_t)rowl * 1024 + colg;
                    ob[off] = acc2[mi][ni][i] + bv + xb[off];
                }
            }
        }
    }
}

// ---------------------------------------------------------------------------
extern "C" void kernel_launch(void* const* d_in, const int* in_sizes, int n_in,
                              void* d_out, int out_size, void* d_ws, size_t ws_size,
                              hipStream_t stream) {
    const float* hidden = (const float*)d_in[0];   // (16, 2048, 1024) fp32
    const float* prob   = (const float*)d_in[1];   // (16, 8) fp32
    const float* w_down = (const float*)d_in[2];   // (8, 256, 1024) fp32
    const float* b_down = (const float*)d_in[3];   // (8, 256) fp32
    const float* w_up   = (const float*)d_in[4];   // (8, 1024, 256) fp32
    const float* b_up   = (const float*)d_in[5];   // (8, 1024) fp32
    float* out = (float*)d_out;                    // (16, 2048, 1024) fp32

    // workspace: merged weights (bf16) + biases (fp32), ~16.1 MB
    u16* Wd = (u16*)d_ws;                               // 16*256*1024 bf16
    u16* Wu = Wd + (size_t)16 * 256 * 1024;             // 16*1024*256 bf16
    float* bd = (float*)(Wu + (size_t)16 * 1024 * 256); // 16*256 f32
    float* bu = bd + 16 * 256;                          // 16*1024 f32

    merge_kernel<<<336, 256, 0, stream>>>(prob, w_down, b_down, w_up, b_up,
                                          Wd, Wu, bd, bu);

    fused_adapter<<<256, 512, 0, stream>>>(hidden, Wd, Wu, bd, bu, out);
}

// Round 4
// 329.016 us; speedup vs baseline: 1.0258x; 1.0082x over previous
//
#include <hip/hip_runtime.h>

// MergeAdapter: out = x + Up_n(relu(Down_n(x))), merged expert weights.
// N=16, S=2048, H=1024, Kexp=8, D=256. fp32 in/out, bf16 MFMA internally.
//
// Round 4: fused kernel, LDS XOR-swizzled (kills the 16-way bank conflicts
// that made round 3 LDS-bound: 2.86e7 conflicts, 151 us), phase-1 double-
// buffered (BK=64, two 48 KB buffers), phase-2 R-fragments in registers
// (af[4][8] = 128 VGPRs) freeing Rs' 64 KB for a double-buffered Wu chunk
// pipeline. Grid = 256 blocks (1/CU), 512 thr = 8 waves.
//
// Swizzle scheme: 16-B slots within a row; physical_slot = logical_slot XOR
// (row & 7) on the low 3 bits. For global_load_lds staging (linear LDS dest)
// the global source column is permuted instead (XOR is involutive).

typedef unsigned short u16;
typedef __bf16 bf16x8 __attribute__((ext_vector_type(8)));
typedef float f32x4 __attribute__((ext_vector_type(4)));

__device__ __forceinline__ u16 f2bf(float f) {
    union { float f; unsigned int i; } v; v.f = f;
    unsigned int r = v.i + 0x7fffu + ((v.i >> 16) & 1u);  // RNE
    return (u16)(r >> 16);
}

__device__ __forceinline__ void gload_lds16(const u16* g, u16* l) {
    __builtin_amdgcn_global_load_lds(
        (const __attribute__((address_space(1))) void*)g,
        (__attribute__((address_space(3))) void*)l,
        16, 0, 0);
}

__device__ __forceinline__ void store8(u16* dst, float4 a, float4 b) {
    union { uint4 u; u16 s[8]; } cv;
    cv.s[0]=f2bf(a.x); cv.s[1]=f2bf(a.y); cv.s[2]=f2bf(a.z); cv.s[3]=f2bf(a.w);
    cv.s[4]=f2bf(b.x); cv.s[5]=f2bf(b.y); cv.s[6]=f2bf(b.z); cv.s[7]=f2bf(b.w);
    *(uint4*)dst = cv.u;
}

// ---------------------------------------------------------------------------
// Kernel 0: merge weights + biases (fp32 in -> bf16 weights / fp32 biases).
// ---------------------------------------------------------------------------
__global__ __launch_bounds__(256)
void merge_kernel(const float* __restrict__ prob,
                  const float* __restrict__ w_down, const float* __restrict__ b_down,
                  const float* __restrict__ w_up,   const float* __restrict__ b_up,
                  u16* __restrict__ Wd, u16* __restrict__ Wu,
                  float* __restrict__ bd, float* __restrict__ bu)
{
    __shared__ float sp[128];          // prob (16 x 8)
    const int tid = threadIdx.x;
    if (tid < 128) sp[tid] = prob[tid];
    __syncthreads();

    const int bid = blockIdx.x;
    const int E = 256 * 1024;

    if (bid < 256) {
        int v = bid * 256 + tid;       // 0..65535 vector slots (8 elems each)
        const bool down = (v < 32768);
        const int vv = down ? v : (v - 32768);
        const float* W = down ? w_down : w_up;
        u16* O = down ? Wd : Wu;
        const size_t e = (size_t)vv * 8;

        float wf[8][8];
        #pragma unroll
        for (int k = 0; k < 8; ++k) {
            const float4 f0 = *(const float4*)(W + (size_t)k * E + e);
            const float4 f1 = *(const float4*)(W + (size_t)k * E + e + 4);
            wf[k][0] = f0.x; wf[k][1] = f0.y; wf[k][2] = f0.z; wf[k][3] = f0.w;
            wf[k][4] = f1.x; wf[k][5] = f1.y; wf[k][6] = f1.z; wf[k][7] = f1.w;
        }
        for (int n = 0; n < 16; ++n) {
            float a[8] = {0.f,0.f,0.f,0.f,0.f,0.f,0.f,0.f};
            #pragma unroll
            for (int k = 0; k < 8; ++k) {
                const float p = sp[n * 8 + k];
                #pragma unroll
                for (int j = 0; j < 8; ++j) a[j] = fmaf(p, wf[k][j], a[j]);
            }
            union { uint4 u; u16 s[8]; } ov;
            #pragma unroll
            for (int j = 0; j < 8; ++j) ov.s[j] = f2bf(a[j]);
            *(uint4*)(O + (size_t)n * E + e) = ov.u;
        }
    } else {
        int idx = (bid - 256) * 256 + tid;   // 0..20479
        if (idx < 16 * 256) {
            const int n = idx >> 8, d = idx & 255;
            float s = 0.f;
            #pragma unroll
            for (int k = 0; k < 8; ++k)
                s = fmaf(sp[n * 8 + k], b_down[k * 256 + d], s);
            bd[idx] = s;
        } else {
            const int i2 = idx - 4096;
            const int n = i2 >> 10, h = i2 & 1023;
            float s = 0.f;
            #pragma unroll
            for (int k = 0; k < 8; ++k)
                s = fmaf(sp[n * 8 + k], b_up[k * 1024 + h], s);
            bu[i2] = s;
        }
    }
}

// ---------------------------------------------------------------------------
// Fused adapter kernel.
// ---------------------------------------------------------------------------
__global__ __launch_bounds__(512, 2)
void fused_adapter(const float* __restrict__ x, const u16* __restrict__ Wd,
                   const u16* __restrict__ Wu, const float* __restrict__ bd,
                   const float* __restrict__ bu, float* __restrict__ out)
{
    __shared__ __align__(16) u16 lds0[32768];   // 64 KB: p1 bufB / Rs / p2 odd chunks
    __shared__ __align__(16) u16 lds1[32768];   // 64 KB: p1 bufA / p2 even chunks

    const int tid  = threadIdx.x;
    const int lane = tid & 63;
    const int wave = tid >> 6;               // 0..7
    const int quad = lane >> 4, rl = lane & 15;
    const int rxl  = rl & 7;

    // swizzle: each batch's 16 M-blocks share one XCD -> Wd/Wu L2-hot
    const int id = blockIdx.x;               // 0..255
    const int r4 = id & 15;
    const int batch = (r4 & 7) * 2 + (r4 >> 3);
    const int mblk  = id >> 4;               // 0..15

    const float* xb  = x  + (size_t)batch * 2048 * 1024 + (size_t)mblk * 128 * 1024;
    const u16*   Wdb = Wd + (size_t)batch * 256 * 1024;
    const u16*   Wub = Wu + (size_t)batch * 1024 * 256;
    const float* bdb = bd + batch * 256;
    const float* bub = bu + batch * 1024;
    float*       ob  = out + (size_t)batch * 2048 * 1024 + (size_t)mblk * 128 * 1024;

    // ================= phase 1: R = relu(x @ Wd^T + bd), dbuf BK=64 ========
    const int wm1 = wave >> 2, wn1 = wave & 3;   // 2x4 over 128x256

    u16* const b0x = lds1;  u16* const b0w = lds1 + 8192;   // even iters
    u16* const b1x = lds0;  u16* const b1w = lds0 + 8192;   // odd iters

    // x staging geometry (2 slots/thread, 8-slot rows, 64-elem rows)
    const int xrow = tid >> 3, xsl = tid & 7;
    const int xdst0 = (xrow * 8 + (xsl ^ (xrow & 7))) * 8;  // swizzled LDS elems
    const int xdst1 = xdst0 + 4096;                          // row+64: same (row&7)
    // Wd staging: 4 gloads/thread; permuted global col (row&7 const over r)
    const int wrow  = tid >> 3;                              // + r*64
    const int wgcol = ((tid & 7) ^ ((tid >> 3) & 7)) * 8;

    f32x4 acc1[4][4] = {};

    // prologue: stage iter 0 into buf0
    {
        const float4 a0 = *(const float4*)(xb + (size_t)xrow * 1024 + xsl * 8);
        const float4 a1 = *(const float4*)(xb + (size_t)xrow * 1024 + xsl * 8 + 4);
        const float4 a2 = *(const float4*)(xb + (size_t)(xrow + 64) * 1024 + xsl * 8);
        const float4 a3 = *(const float4*)(xb + (size_t)(xrow + 64) * 1024 + xsl * 8 + 4);
        #pragma unroll
        for (int r = 0; r < 4; ++r)
            gload_lds16(Wdb + (size_t)(r * 64 + wrow) * 1024 + wgcol,
                        b0w + (size_t)(r * 512 + wave * 64) * 8);
        store8(b0x + xdst0, a0, a1);
        store8(b0x + xdst1, a2, a3);
    }
    __syncthreads();

    for (int it = 0; it < 16; ++it) {
        u16* cx = (it & 1) ? b1x : b0x;
        u16* cw = (it & 1) ? b1w : b0w;
        u16* nx = (it & 1) ? b0x : b1x;
        u16* nw = (it & 1) ? b0w : b1w;
        const int k1 = (it + 1) * 64;

        float4 a0, a1, a2, a3;
        if (it < 15) {
            a0 = *(const float4*)(xb + (size_t)xrow * 1024 + k1 + xsl * 8);
            a1 = *(const float4*)(xb + (size_t)xrow * 1024 + k1 + xsl * 8 + 4);
            a2 = *(const float4*)(xb + (size_t)(xrow + 64) * 1024 + k1 + xsl * 8);
            a3 = *(const float4*)(xb + (size_t)(xrow + 64) * 1024 + k1 + xsl * 8 + 4);
            #pragma unroll
            for (int r = 0; r < 4; ++r)
                gload_lds16(Wdb + (size_t)(r * 64 + wrow) * 1024 + k1 + wgcol,
                            nw + (size_t)(r * 512 + wave * 64) * 8);
        }

        #pragma unroll
        for (int kk = 0; kk < 64; kk += 32) {
            bf16x8 av[4], bv[4];
            #pragma unroll
            for (int mi = 0; mi < 4; ++mi)
                av[mi] = *(const bf16x8*)(cx + (wm1 * 64 + mi * 16 + rl) * 64
                                          + ((kk / 8 + quad) ^ rxl) * 8);
            #pragma unroll
            for (int ni = 0; ni < 4; ++ni)
                bv[ni] = *(const bf16x8*)(cw + (wn1 * 64 + ni * 16 + rl) * 64
                                          + ((kk / 8 + quad) ^ rxl) * 8);
            #pragma unroll
            for (int mi = 0; mi < 4; ++mi)
                #pragma unroll
                for (int ni = 0; ni < 4; ++ni)
                    acc1[mi][ni] = __builtin_amdgcn_mfma_f32_16x16x32_bf16(
                        av[mi], bv[ni], acc1[mi][ni], 0, 0, 0);
        }

        if (it < 15) { store8(nx + xdst0, a0, a1); store8(nx + xdst1, a2, a3); }
        __syncthreads();
    }

    // epilogue 1: bias + relu -> Rs (lds0), 32-slot rows, swizzled
    #pragma unroll
    for (int ni = 0; ni < 4; ++ni) {
        const int col = wn1 * 64 + ni * 16 + rl;
        const float bv = bdb[col];
        const int lbc = col >> 3, hi = lbc & 24, c7 = lbc & 7, cl = col & 7;
        #pragma unroll
        for (int mi = 0; mi < 4; ++mi)
            #pragma unroll
            for (int i = 0; i < 4; ++i) {
                const int row = wm1 * 64 + mi * 16 + quad * 4 + i;
                const int phys = hi | (c7 ^ (row & 7));
                lds0[row * 256 + phys * 8 + cl] =
                    f2bf(fmaxf(acc1[mi][ni][i] + bv, 0.0f));
            }
    }
    __syncthreads();

    // ================= phase 2: out = x + R @ Wu^T + bu ====================
    const int wm2 = wave >> 2, wn2 = wave & 3;   // rows 2x / cols 4x per chunk

    // Wu chunk staging geometry: 8 gloads/thread, 32-slot rows (256 elems)
    const int srow = tid >> 5, ss = tid & 31;    // row = c*128 + rr*16 + srow
    const int wugcol = ((ss & 24) | ((ss & 7) ^ (srow & 7))) * 8;

    auto stage_wu = [&](int c, u16* buf) {
        #pragma unroll
        for (int rr = 0; rr < 8; ++rr)
            gload_lds16(Wub + (size_t)(c * 128 + rr * 16 + srow) * 256 + wugcol,
                        buf + (size_t)(rr * 512 + wave * 64) * 8);
    };

    stage_wu(0, lds1);

    // hoist R A-fragments to registers: af[mi][t], 128 VGPRs
    bf16x8 af[4][8];
    #pragma unroll
    for (int mi = 0; mi < 4; ++mi) {
        const int rowb = (wm2 * 64 + mi * 16 + rl) * 256;
        #pragma unroll
        for (int t = 0; t < 8; ++t) {
            const int lb = t * 4 + quad;
            const int phys = (lb & 24) | ((lb & 7) ^ rxl);
            af[mi][t] = *(const bf16x8*)(lds0 + rowb + phys * 8);
        }
    }
    __syncthreads();   // af complete (lds0 free) + chunk 0 DMA drained

    u16* cur = lds1;
    u16* nxt = lds0;
    for (int c = 0; c < 8; ++c) {
        if (c < 7) stage_wu(c + 1, nxt);

        f32x4 acc2[4][2] = {};
        #pragma unroll
        for (int t = 0; t < 8; ++t) {
            bf16x8 bv[2];
            #pragma unroll
            for (int ni = 0; ni < 2; ++ni) {
                const int rowb = (wn2 * 32 + ni * 16 + rl) * 256;
                const int lb = t * 4 + quad;
                const int phys = (lb & 24) | ((lb & 7) ^ rxl);
                bv[ni] = *(const bf16x8*)(cur + rowb + phys * 8);
            }
            #pragma unroll
            for (int mi = 0; mi < 4; ++mi)
                #pragma unroll
                for (int ni = 0; ni < 2; ++ni)
                    acc2[mi][ni] = __builtin_amdgcn_mfma_f32_16x16x32_bf16(
                        af[mi][t], bv[ni], acc2[mi][ni], 0, 0, 0);
        }

        // epilogue 2: bias + fp32 residual -> fp32 out
        #pragma unroll
        for (int ni = 0; ni < 2; ++ni) {
            const int colg = c * 128 + wn2 * 32 + ni * 16 + rl;
            const float bv = bub[colg];
            #pragma unroll
            for (int mi = 0; mi < 4; ++mi)
                #pragma unroll
                for (int i = 0; i < 4; ++i) {
                    const int rowl = wm2 * 64 + mi * 16 + quad * 4 + i;
                    const size_t off = (size_t)rowl * 1024 + colg;
                    ob[off] = acc2[mi][ni][i] + bv + xb[off];
                }
        }

        if (c < 7) {
            u16* t2 = cur; cur = nxt; nxt = t2;
            __syncthreads();   // drains chunk c+1 DMA; frees old cur for c+2
        }
    }
}

// ---------------------------------------------------------------------------
extern "C" void kernel_launch(void* const* d_in, const int* in_sizes, int n_in,
                              void* d_out, int out_size, void* d_ws, size_t ws_size,
                              hipStream_t stream) {
    const float* hidden = (const float*)d_in[0];   // (16, 2048, 1024) fp32
    const float* prob   = (const float*)d_in[1];   // (16, 8) fp32
    const float* w_down = (const float*)d_in[2];   // (8, 256, 1024) fp32
    const float* b_down = (const float*)d_in[3];   // (8, 256) fp32
    const float* w_up   = (const float*)d_in[4];   // (8, 1024, 256) fp32
    const float* b_up   = (const float*)d_in[5];   // (8, 1024) fp32
    float* out = (float*)d_out;                    // (16, 2048, 1024) fp32

    // workspace: merged weights (bf16) + biases (fp32), ~16.1 MB
    u16* Wd = (u16*)d_ws;                               // 16*256*1024 bf16
    u16* Wu = Wd + (size_t)16 * 256 * 1024;             // 16*1024*256 bf16
    float* bd = (float*)(Wu + (size_t)16 * 1024 * 256); // 16*256 f32
    float* bu = bd + 16 * 256;                          // 16*1024 f32

    merge_kernel<<<336, 256, 0, stream>>>(prob, w_down, b_down, w_up, b_up,
                                          Wd, Wu, bd, bu);

    fused_adapter<<<256, 512, 0, stream>>>(hidden, Wd, Wu, bd, bu, out);
}